// Round 15
// baseline (75.121 us; speedup 1.0000x reference)
//
#include <hip/hip_runtime.h>
#include <hip/hip_fp16.h>
#include <cstdint>
#include <cstddef>

#define IDIM 192
#define NSAMP 128
#define NRAYS 16384
#define NVOX (IDIM * IDIM * IDIM)     // 7077888
#define NFUSE (NVOX / 256)            // 27648 fuse tiles
#define NSORTB (NRAYS / 4)            // 4096 sort blocks (4 rays each, 1/wave)
#define NBLK (NFUSE + NSORTB)         // 31744
#define SORT_PERIOD 7                 // 1 sort block per 7 (4096*7=28672<=NBLK)
#define SORT_LIM (NSORTB * SORT_PERIOD)

// Brick layout: 2x2x4 voxels = 16 entries x 4B = exactly one 64B cache line.
//   idx(x,y,z) = f(x) + g(y) + h(z)
//   f(x) = (x>>1)*73728 + (x&1)*8      (73728 = 96*48*16)
//   g(y) = (y>>1)*768   + (y&1)*4      (768   = 48*16)
//   h(z) = (z>>2)*16    + (z&3)

__device__ __forceinline__ uint32_t rotl32(uint32_t x, int r) {
    return (x << r) | (x >> (32 - r));
}

// JAX threefry2x32, key (0,1), partitionable path: bits(i) = x0 ^ x1 of TF((0,1),(0,i))
__device__ __forceinline__ uint32_t threefry_bits(uint32_t i) {
    const uint32_t ks0 = 0u;
    const uint32_t ks1 = 1u;
    const uint32_t ks2 = 0x1BD11BDAu ^ ks0 ^ ks1;  // 0x1BD11BDB
    uint32_t x0 = 0u + ks0;
    uint32_t x1 = i + ks1;
#define TF_ROUND(r) { x0 += x1; x1 = rotl32(x1, (r)); x1 ^= x0; }
    TF_ROUND(13) TF_ROUND(15) TF_ROUND(26) TF_ROUND(6)
    x0 += ks1; x1 += ks2 + 1u;
    TF_ROUND(17) TF_ROUND(29) TF_ROUND(16) TF_ROUND(24)
    x0 += ks2; x1 += ks0 + 2u;
    TF_ROUND(13) TF_ROUND(15) TF_ROUND(26) TF_ROUND(6)
    x0 += ks0; x1 += ks1 + 3u;
    TF_ROUND(17) TF_ROUND(29) TF_ROUND(16) TF_ROUND(24)
    x0 += ks1; x1 += ks2 + 4u;
    TF_ROUND(13) TF_ROUND(15) TF_ROUND(26) TF_ROUND(6)
    x0 += ks2; x1 += ks0 + 5u;
#undef TF_ROUND
    return x0 ^ x1;
}

// Mixed kernel 1: fuse tiles (memory-bound streaming, float4-vectorized
// staging) + 1-in-7 sort blocks (register/shuffle-only RNG + bitonic sort).
__global__ __launch_bounds__(256)
void prep_kernel(const float* __restrict__ grid, const float* __restrict__ opacity,
                 const float* __restrict__ x, const float* __restrict__ dvec,
                 __half2* __restrict__ tab, float* __restrict__ sts) {
    const int b = blockIdx.x;
    const bool is_sort = (b < SORT_LIM) && (b % SORT_PERIOD == 3);

    if (is_sort) {
        // ---- sortgen: 4 rays per block, one per wave; registers only ----
        const int q = b / SORT_PERIOD;          // 0..4095
        const int wv = threadIdx.x >> 6;
        const int lane = threadIdx.x & 63;
        const int r = q * 4 + wv;

        const float ox = x[r * 3 + 0], oy = x[r * 3 + 1], oz = x[r * 3 + 2];
        const float dx = dvec[r * 3 + 0], dy = dvec[r * 3 + 1], dz = dvec[r * 3 + 2];
        const float inv_dx = 1.f / dx, inv_dy = 1.f / dy, inv_dz = 1.f / dz;
        const float INF = 7077888.f;  // 192^3
        const float BMAX = (float)(IDIM - 1);

        float tmin = -INF, tmax = INF;
        {
            float t0 = (0.f - ox) * inv_dx, t1 = (BMAX - ox) * inv_dx;
            tmin = fmaxf(tmin, fminf(t0, t1)); tmax = fminf(tmax, fmaxf(t0, t1));
            t0 = (0.f - oy) * inv_dy; t1 = (BMAX - oy) * inv_dy;
            tmin = fmaxf(tmin, fminf(t0, t1)); tmax = fminf(tmax, fmaxf(t0, t1));
            t0 = (0.f - oz) * inv_dz; t1 = (BMAX - oz) * inv_dz;
            tmin = fmaxf(tmin, fminf(t0, t1)); tmax = fminf(tmax, fmaxf(t0, t1));
        }

        const uint32_t i0 = (uint32_t)(r * NSAMP + lane);
        const uint32_t b0 = threefry_bits(i0);
        const uint32_t b1 = threefry_bits(i0 + 64u);
        float u0 = __uint_as_float((b0 >> 9) | 0x3f800000u) - 1.0f;
        float u1 = __uint_as_float((b1 >> 9) | 0x3f800000u) - 1.0f;
        u0 = fmaxf(0.f, u0);
        u1 = fmaxf(0.f, u1);
        float v0 = tmin + u0 * (tmax - tmin);
        float v1 = tmin + u1 * (tmax - tmin);

#define BSTEP(J, K)                                                            \
        {                                                                      \
            const float p0 = __shfl_xor(v0, (J));                              \
            const float p1 = __shfl_xor(v1, (J));                              \
            const bool lower = (lane & (J)) == 0;                              \
            const bool tm0 = (((lane) & (K)) == 0) == lower;                   \
            const bool tm1 = ((((lane) + 64) & (K)) == 0) == lower;            \
            v0 = tm0 ? fminf(v0, p0) : fmaxf(v0, p0);                          \
            v1 = tm1 ? fminf(v1, p1) : fmaxf(v1, p1);                          \
        }
        #pragma unroll
        for (int k = 2; k <= 64; k <<= 1) {
            #pragma unroll
            for (int j = k >> 1; j >= 1; j >>= 1) BSTEP(j, k)
        }
        {
            const float mn = fminf(v0, v1), mx = fmaxf(v0, v1);
            v0 = mn; v1 = mx;
        }
        #pragma unroll
        for (int j = 32; j >= 1; j >>= 1) BSTEP(j, 128)
#undef BSTEP
        sts[r * NSAMP + lane] = v0;
        sts[r * NSAMP + 64 + lane] = v1;
    } else {
        // ---- fuse tile: float4-vectorized staging (2304 floats = 576 f4) ----
        __shared__ __align__(16) float sh[256 * 9];
        float4* shv = reinterpret_cast<float4*>(sh);
        const int t = threadIdx.x;
        const int nsb = (b < SORT_LIM) ? (b + 3) / SORT_PERIOD : NSORTB;
        const int base = (b - nsb) * 256;
        const float4* gv = reinterpret_cast<const float4*>(grid + (size_t)base * 9);
        shv[t] = gv[t];
        shv[t + 256] = gv[t + 256];
        if (t < 64) shv[t + 512] = gv[t + 512];
        __syncthreads();
        float s = 0.f;
        #pragma unroll
        for (int c = 0; c < 9; ++c) s += sh[t * 9 + c];
        const int v = base + t;
        const int xq = v / (IDIM * IDIM);
        const int rem = v - xq * (IDIM * IDIM);
        const int yq = rem / IDIM;
        const int zq = rem - yq * IDIM;
        const int idx = (xq >> 1) * 73728 + ((xq & 1) << 3)
                      + (yq >> 1) * 768   + ((yq & 1) << 2)
                      + (zq >> 2) * 16    + (zq & 3);
        tab[idx] = __floats2half2_rn(s, opacity[v]);
    }
}

// Kernel 2: gather + composite only. One ray per wave; sorted samples come
// from sts via two coalesced loads. Rounds of 32 samples with 2 lanes/sample;
// wave-uniform early exit at cum >= 10.
__global__ __launch_bounds__(128, 8)
void rf_kernel(const float* __restrict__ x, const float* __restrict__ d,
               const __half2* __restrict__ tab, const float* __restrict__ sts,
               float* __restrict__ out) {
    const int wave = threadIdx.x >> 6;
    const int lane = threadIdx.x & 63;
    const int r = blockIdx.x * 2 + wave;

    // hoisted independent loads
    const float v0 = sts[r * NSAMP + lane];        // sorted[lane]
    const float v1 = sts[r * NSAMP + 64 + lane];   // sorted[lane+64]
    const float ox = x[r * 3 + 0], oy = x[r * 3 + 1], oz = x[r * 3 + 2];
    const float dx = d[r * 3 + 0], dy = d[r * 3 + 1], dz = d[r * 3 + 2];

    const int odd = lane & 1;
    const int hs  = lane >> 1;
    float cumRay = 0.f, acc = 0.f;

    for (int k = 0; k < 4; ++k) {
        const int sk = k * 32 + hs;
        const bool valid = (sk < NSAMP - 1);

        float ts, tn;
        if (k < 2) {
            ts = __shfl(v0, sk);
            const float tnv = __shfl(v0, (sk + 1 > 63) ? 63 : sk + 1);
            const float s64 = __shfl(v1, 0);
            tn = (sk == 63) ? s64 : tnv;
        } else {
            ts = __shfl(v1, sk - 64);
            const int ti = sk - 63;
            tn = __shfl(v1, (ti > 63) ? 63 : ti);
        }

        const float px = ox + ts * dx;
        const float py = oy + ts * dy;
        const float pz = oz + ts * dz;
        int ix = (int)floorf(px); ix = ix < 0 ? 0 : (ix > IDIM - 2 ? IDIM - 2 : ix);
        int iy = (int)floorf(py); iy = iy < 0 ? 0 : (iy > IDIM - 2 ? IDIM - 2 : iy);
        int iz = (int)floorf(pz); iz = iz < 0 ? 0 : (iz > IDIM - 2 ? IDIM - 2 : iz);
        const float fx = px - (float)ix;
        const float fy = py - (float)iy;
        const float fz = pz - (float)iz;
        const float wxs = odd ? fx : (1.f - fx);
        const float wy0 = 1.f - fy, wy1 = fy;
        const float wz0 = 1.f - fz, wz1 = fz;
        const int xs = ix + odd;
        const int fs = (xs >> 1) * 73728 + ((xs & 1) << 3);
        const int g0 = (iy >> 1) * 768 + ((iy & 1) << 2);
        const int g1 = ((iy + 1) >> 1) * 768 + (((iy + 1) & 1) << 2);
        const int h0 = (iz >> 2) * 16 + (iz & 3);
        const int h1 = ((iz + 1) >> 2) * 16 + ((iz + 1) & 3);
        const float2 c00 = __half22float2(tab[fs + g0 + h0]);
        const float2 c01 = __half22float2(tab[fs + g0 + h1]);
        const float2 c10 = __half22float2(tab[fs + g1 + h0]);
        const float2 c11 = __half22float2(tab[fs + g1 + h1]);
        float hp = wxs * (wy0 * (wz0 * c00.x + wz1 * c01.x) +
                          wy1 * (wz0 * c10.x + wz1 * c11.x));
        float op = wxs * (wy0 * (wz0 * c00.y + wz1 * c01.y) +
                          wy1 * (wz0 * c10.y + wz1 * c11.y));
        const float hsv = hp + __shfl_xor(hp, 1);
        const float opv = op + __shfl_xor(op, 1);

        const float cur = (valid && !odd) ? (tn - ts) * opv : 0.f;
        float incl = cur;
        #pragma unroll
        for (int off = 1; off < 64; off <<= 1) {
            const float tmp = __shfl_up(incl, off);
            if (lane >= off) incl += tmp;
        }
        if (valid && !odd) {
            const float excl = cumRay + incl - cur;
            const float color = 1.f / (1.f + __expf(-hsv));
            acc += __expf(-excl) * (1.f - __expf(-cur)) * color;
        }
        cumRay += __shfl(incl, 63);
        if (cumRay >= 10.f) break;
    }

    #pragma unroll
    for (int off = 32; off > 0; off >>= 1) acc += __shfl_down(acc, off);
    if (lane == 0) out[r] = acc;
}

extern "C" void kernel_launch(void* const* d_in, const int* in_sizes, int n_in,
                              void* d_out, int out_size, void* d_ws, size_t ws_size,
                              hipStream_t stream) {
    const float* x       = (const float*)d_in[0];
    const float* d       = (const float*)d_in[1];
    const float* grid    = (const float*)d_in[2];
    const float* opacity = (const float*)d_in[3];
    float* out = (float*)d_out;

    __half2* tab = (__half2*)d_ws;
    float* sts = (float*)((char*)d_ws + (size_t)NVOX * sizeof(__half2));

    prep_kernel<<<NBLK, 256, 0, stream>>>(grid, opacity, x, d, tab, sts);
    rf_kernel<<<NRAYS / 2, 128, 0, stream>>>(x, d, tab, sts, out);
}

// Round 16
// 71.345 us; speedup vs baseline: 1.0529x; 1.0529x over previous
//
#include <hip/hip_runtime.h>
#include <hip/hip_fp16.h>
#include <cstdint>
#include <cstddef>

#define IDIM 192
#define NSAMP 128
#define NRAYS 16384
#define NVOX (IDIM * IDIM * IDIM)     // 7077888
#define NFUSE (NVOX / 256)            // 27648 fuse tiles
#define NSORTB (NRAYS / 4)            // 4096 sort blocks (4 rays each, 1/wave)
#define NBLK (NFUSE + NSORTB)         // 31744
#define SORT_PERIOD 7                 // 1 sort block per 7 (4096*7=28672<=NBLK)
#define SORT_LIM (NSORTB * SORT_PERIOD)

// Brick layout: 2x2x4 voxels = 16 entries x 4B = exactly one 64B cache line.
//   idx(x,y,z) = f(x) + g(y) + h(z)
//   f(x) = (x>>1)*73728 + (x&1)*8      (73728 = 96*48*16)
//   g(y) = (y>>1)*768   + (y&1)*4      (768   = 48*16)
//   h(z) = (z>>2)*16    + (z&3)

__device__ __forceinline__ uint32_t rotl32(uint32_t x, int r) {
    return (x << r) | (x >> (32 - r));
}

// JAX threefry2x32, key (0,1), partitionable path: bits(i) = x0 ^ x1 of TF((0,1),(0,i))
__device__ __forceinline__ uint32_t threefry_bits(uint32_t i) {
    const uint32_t ks0 = 0u;
    const uint32_t ks1 = 1u;
    const uint32_t ks2 = 0x1BD11BDAu ^ ks0 ^ ks1;  // 0x1BD11BDB
    uint32_t x0 = 0u + ks0;
    uint32_t x1 = i + ks1;
#define TF_ROUND(r) { x0 += x1; x1 = rotl32(x1, (r)); x1 ^= x0; }
    TF_ROUND(13) TF_ROUND(15) TF_ROUND(26) TF_ROUND(6)
    x0 += ks1; x1 += ks2 + 1u;
    TF_ROUND(17) TF_ROUND(29) TF_ROUND(16) TF_ROUND(24)
    x0 += ks2; x1 += ks0 + 2u;
    TF_ROUND(13) TF_ROUND(15) TF_ROUND(26) TF_ROUND(6)
    x0 += ks0; x1 += ks1 + 3u;
    TF_ROUND(17) TF_ROUND(29) TF_ROUND(16) TF_ROUND(24)
    x0 += ks1; x1 += ks2 + 4u;
    TF_ROUND(13) TF_ROUND(15) TF_ROUND(26) TF_ROUND(6)
    x0 += ks2; x1 += ks0 + 5u;
#undef TF_ROUND
    return x0 ^ x1;
}

// Mixed kernel 1: fuse tiles (memory-bound streaming) + 1-in-7 sort blocks
// (register/shuffle-only RNG + bitonic sort, zero LDS -> hides in the
// fuse blocks' memory stalls). Sort blocks write sorted samples to sts.
__global__ __launch_bounds__(256)
void prep_kernel(const float* __restrict__ grid, const float* __restrict__ opacity,
                 const float* __restrict__ x, const float* __restrict__ dvec,
                 __half2* __restrict__ tab, float* __restrict__ sts) {
    const int b = blockIdx.x;
    const bool is_sort = (b < SORT_LIM) && (b % SORT_PERIOD == 3);

    if (is_sort) {
        // ---- sortgen: 4 rays per block, one per wave; registers only ----
        const int q = b / SORT_PERIOD;          // 0..4095
        const int wv = threadIdx.x >> 6;
        const int lane = threadIdx.x & 63;
        const int r = q * 4 + wv;

        const float ox = x[r * 3 + 0], oy = x[r * 3 + 1], oz = x[r * 3 + 2];
        const float dx = dvec[r * 3 + 0], dy = dvec[r * 3 + 1], dz = dvec[r * 3 + 2];
        const float inv_dx = 1.f / dx, inv_dy = 1.f / dy, inv_dz = 1.f / dz;
        const float INF = 7077888.f;  // 192^3
        const float BMAX = (float)(IDIM - 1);

        float tmin = -INF, tmax = INF;
        {
            float t0 = (0.f - ox) * inv_dx, t1 = (BMAX - ox) * inv_dx;
            tmin = fmaxf(tmin, fminf(t0, t1)); tmax = fminf(tmax, fmaxf(t0, t1));
            t0 = (0.f - oy) * inv_dy; t1 = (BMAX - oy) * inv_dy;
            tmin = fmaxf(tmin, fminf(t0, t1)); tmax = fminf(tmax, fmaxf(t0, t1));
            t0 = (0.f - oz) * inv_dz; t1 = (BMAX - oz) * inv_dz;
            tmin = fmaxf(tmin, fminf(t0, t1)); tmax = fminf(tmax, fmaxf(t0, t1));
        }

        const uint32_t i0 = (uint32_t)(r * NSAMP + lane);
        const uint32_t b0 = threefry_bits(i0);
        const uint32_t b1 = threefry_bits(i0 + 64u);
        float u0 = __uint_as_float((b0 >> 9) | 0x3f800000u) - 1.0f;
        float u1 = __uint_as_float((b1 >> 9) | 0x3f800000u) - 1.0f;
        u0 = fmaxf(0.f, u0);
        u1 = fmaxf(0.f, u1);
        float v0 = tmin + u0 * (tmax - tmin);
        float v1 = tmin + u1 * (tmax - tmin);

#define BSTEP(J, K)                                                            \
        {                                                                      \
            const float p0 = __shfl_xor(v0, (J));                              \
            const float p1 = __shfl_xor(v1, (J));                              \
            const bool lower = (lane & (J)) == 0;                              \
            const bool tm0 = (((lane) & (K)) == 0) == lower;                   \
            const bool tm1 = ((((lane) + 64) & (K)) == 0) == lower;            \
            v0 = tm0 ? fminf(v0, p0) : fmaxf(v0, p0);                          \
            v1 = tm1 ? fminf(v1, p1) : fmaxf(v1, p1);                          \
        }
        #pragma unroll
        for (int k = 2; k <= 64; k <<= 1) {
            #pragma unroll
            for (int j = k >> 1; j >= 1; j >>= 1) BSTEP(j, k)
        }
        {
            const float mn = fminf(v0, v1), mx = fmaxf(v0, v1);
            v0 = mn; v1 = mx;
        }
        #pragma unroll
        for (int j = 32; j >= 1; j >>= 1) BSTEP(j, 128)
#undef BSTEP
        // v0 = sorted[lane], v1 = sorted[lane+64]; coalesced store
        sts[r * NSAMP + lane] = v0;
        sts[r * NSAMP + 64 + lane] = v1;
    } else {
        // ---- fuse tile: tab[brick(v)] = half2{sum_c grid[v][c], opacity[v]} ----
        __shared__ float sh[256 * 9];
        const int t = threadIdx.x;
        const int nsb = (b < SORT_LIM) ? (b + 3) / SORT_PERIOD : NSORTB;
        const int base = (b - nsb) * 256;
        const float* gp = grid + (size_t)base * 9;
        #pragma unroll
        for (int i = 0; i < 9; ++i) {
            sh[i * 256 + t] = gp[i * 256 + t];
        }
        __syncthreads();
        float s = 0.f;
        #pragma unroll
        for (int c = 0; c < 9; ++c) s += sh[t * 9 + c];
        const int v = base + t;
        const int xq = v / (IDIM * IDIM);
        const int rem = v - xq * (IDIM * IDIM);
        const int yq = rem / IDIM;
        const int zq = rem - yq * IDIM;
        const int idx = (xq >> 1) * 73728 + ((xq & 1) << 3)
                      + (yq >> 1) * 768   + ((yq & 1) << 2)
                      + (zq >> 2) * 16    + (zq & 3);
        tab[idx] = __floats2half2_rn(s, opacity[v]);
    }
}

// Kernel 2: gather + composite only. One ray per wave; sorted samples come
// from sts via two coalesced loads into (v0, v1). Rounds of 32 samples with
// 2 lanes/sample; wave-uniform early exit at cum >= 10.
__global__ __launch_bounds__(128, 8)
void rf_kernel(const float* __restrict__ x, const float* __restrict__ d,
               const __half2* __restrict__ tab, const float* __restrict__ sts,
               float* __restrict__ out) {
    const int wave = threadIdx.x >> 6;
    const int lane = threadIdx.x & 63;
    const int r = blockIdx.x * 2 + wave;

    const float ox = x[r * 3 + 0], oy = x[r * 3 + 1], oz = x[r * 3 + 2];
    const float dx = d[r * 3 + 0], dy = d[r * 3 + 1], dz = d[r * 3 + 2];

    const float v0 = sts[r * NSAMP + lane];        // sorted[lane]
    const float v1 = sts[r * NSAMP + 64 + lane];   // sorted[lane+64]

    const int odd = lane & 1;
    const int hs  = lane >> 1;
    float cumRay = 0.f, acc = 0.f;

    for (int k = 0; k < 4; ++k) {
        const int sk = k * 32 + hs;
        const bool valid = (sk < NSAMP - 1);

        float ts, tn;
        if (k < 2) {
            ts = __shfl(v0, sk);
            const float tnv = __shfl(v0, (sk + 1 > 63) ? 63 : sk + 1);
            const float s64 = __shfl(v1, 0);
            tn = (sk == 63) ? s64 : tnv;
        } else {
            ts = __shfl(v1, sk - 64);
            const int ti = sk - 63;
            tn = __shfl(v1, (ti > 63) ? 63 : ti);
        }

        const float px = ox + ts * dx;
        const float py = oy + ts * dy;
        const float pz = oz + ts * dz;
        int ix = (int)floorf(px); ix = ix < 0 ? 0 : (ix > IDIM - 2 ? IDIM - 2 : ix);
        int iy = (int)floorf(py); iy = iy < 0 ? 0 : (iy > IDIM - 2 ? IDIM - 2 : iy);
        int iz = (int)floorf(pz); iz = iz < 0 ? 0 : (iz > IDIM - 2 ? IDIM - 2 : iz);
        const float fx = px - (float)ix;
        const float fy = py - (float)iy;
        const float fz = pz - (float)iz;
        const float wxs = odd ? fx : (1.f - fx);
        const float wy0 = 1.f - fy, wy1 = fy;
        const float wz0 = 1.f - fz, wz1 = fz;
        const int xs = ix + odd;
        const int fs = (xs >> 1) * 73728 + ((xs & 1) << 3);
        const int g0 = (iy >> 1) * 768 + ((iy & 1) << 2);
        const int g1 = ((iy + 1) >> 1) * 768 + (((iy + 1) & 1) << 2);
        const int h0 = (iz >> 2) * 16 + (iz & 3);
        const int h1 = ((iz + 1) >> 2) * 16 + ((iz + 1) & 3);
        const float2 c00 = __half22float2(tab[fs + g0 + h0]);
        const float2 c01 = __half22float2(tab[fs + g0 + h1]);
        const float2 c10 = __half22float2(tab[fs + g1 + h0]);
        const float2 c11 = __half22float2(tab[fs + g1 + h1]);
        float hp = wxs * (wy0 * (wz0 * c00.x + wz1 * c01.x) +
                          wy1 * (wz0 * c10.x + wz1 * c11.x));
        float op = wxs * (wy0 * (wz0 * c00.y + wz1 * c01.y) +
                          wy1 * (wz0 * c10.y + wz1 * c11.y));
        const float hsv = hp + __shfl_xor(hp, 1);
        const float opv = op + __shfl_xor(op, 1);

        const float cur = (valid && !odd) ? (tn - ts) * opv : 0.f;
        float incl = cur;
        #pragma unroll
        for (int off = 1; off < 64; off <<= 1) {
            const float tmp = __shfl_up(incl, off);
            if (lane >= off) incl += tmp;
        }
        if (valid && !odd) {
            const float excl = cumRay + incl - cur;
            const float color = 1.f / (1.f + __expf(-hsv));
            acc += __expf(-excl) * (1.f - __expf(-cur)) * color;
        }
        cumRay += __shfl(incl, 63);
        if (cumRay >= 10.f) break;
    }

    #pragma unroll
    for (int off = 32; off > 0; off >>= 1) acc += __shfl_down(acc, off);
    if (lane == 0) out[r] = acc;
}

extern "C" void kernel_launch(void* const* d_in, const int* in_sizes, int n_in,
                              void* d_out, int out_size, void* d_ws, size_t ws_size,
                              hipStream_t stream) {
    const float* x       = (const float*)d_in[0];
    const float* d       = (const float*)d_in[1];
    const float* grid    = (const float*)d_in[2];
    const float* opacity = (const float*)d_in[3];
    float* out = (float*)d_out;

    __half2* tab = (__half2*)d_ws;
    float* sts = (float*)((char*)d_ws + (size_t)NVOX * sizeof(__half2));

    prep_kernel<<<NBLK, 256, 0, stream>>>(grid, opacity, x, d, tab, sts);
    rf_kernel<<<NRAYS / 2, 128, 0, stream>>>(x, d, tab, sts, out);
}